// Round 1
// baseline (508.766 us; speedup 1.0000x reference)
//
#include <hip/hip_runtime.h>
#include <hip/hip_bf16.h>

#define NC     80
#define BATCH  1048576
#define CHUNKS (BATCH / 32)          // 32768 K-chunks of 32 rows
#define NBLK   1024
#define NTHR   256
#define NWAVES (NBLK * NTHR / 64)    // 4096 waves, 8 chunks/wave

using bf16x8 = __attribute__((ext_vector_type(8))) __bf16;
using f32x4  = __attribute__((ext_vector_type(4))) float;

// Stage 1: G = label^T @ label (upper-triangle 16x16 tiles), bf16 MFMA.
// Labels are exactly {0,1} -> bf16 truncation is exact; all partial sums are
// integers < 2^24 -> fp32 atomicAdd accumulation is exact & order-independent.
__global__ __launch_bounds__(NTHR) void gram_kernel(const float* __restrict__ label,
                                                    float* __restrict__ G) {
    __shared__ float Gs[NC * NC];
    const int tid = threadIdx.x;
    for (int u = tid; u < NC * NC; u += NTHR) Gs[u] = 0.0f;

    const int lane = tid & 63;
    const int m    = lane & 15;   // class-within-tile (output col / frag row)
    const int quad = lane >> 4;   // k-subchunk selector

    const int wid = (blockIdx.x * NTHR + tid) >> 6;   // global wave id

    f32x4 acc[15];
#pragma unroll
    for (int t = 0; t < 15; ++t) acc[t] = (f32x4){0.f, 0.f, 0.f, 0.f};

    for (int c = wid; c < CHUNKS; c += NWAVES) {
        // lane reads 8 fp32 per fragment: rows kbase+quad*8+j, col 16t+m.
        // Rows are 320 B = 5 aligned 64B lines; each line fetched exactly once.
        const float* base = label + (size_t)(c * 32 + quad * 8) * NC + m;
        float v[8][5];
#pragma unroll
        for (int j = 0; j < 8; ++j) {
            const float* rp = base + j * NC;
#pragma unroll
            for (int t = 0; t < 5; ++t) v[j][t] = rp[t * 16];
        }

        // fp32 -> bf16 by top-16-bit truncation (exact for 0.0 / 1.0)
        bf16x8 frag[5];
#pragma unroll
        for (int t = 0; t < 5; ++t) {
            union { unsigned int u[4]; bf16x8 b; } cv;
#pragma unroll
            for (int p = 0; p < 4; ++p) {
                unsigned lo = __float_as_uint(v[2 * p][t]) >> 16;
                unsigned hi = __float_as_uint(v[2 * p + 1][t]) & 0xFFFF0000u;
                cv.u[p] = hi | lo;
            }
            frag[t] = cv.b;
        }

        // G tile (ti,tj) = frag[ti]^T-as-A x frag[tj]-as-B ; upper triangle only
        int idx = 0;
#pragma unroll
        for (int ti = 0; ti < 5; ++ti)
#pragma unroll
            for (int tj = ti; tj < 5; ++tj) {
                acc[idx] = __builtin_amdgcn_mfma_f32_16x16x32_bf16(
                    frag[ti], frag[tj], acc[idx], 0, 0, 0);
                ++idx;
            }
    }

    __syncthreads();   // Gs zero-init complete across all waves

    // wave accs -> LDS (C/D layout: col = lane&15, row = quad*4 + reg)
    {
        int idx = 0;
#pragma unroll
        for (int ti = 0; ti < 5; ++ti)
#pragma unroll
            for (int tj = ti; tj < 5; ++tj) {
#pragma unroll
                for (int r = 0; r < 4; ++r) {
                    int row = 16 * ti + quad * 4 + r;
                    int col = 16 * tj + m;
                    atomicAdd(&Gs[row * NC + col], acc[idx][r]);
                }
                ++idx;
            }
    }
    __syncthreads();

    // block partial -> global (upper-triangle tiles only; 15 atomics/thread)
    {
        int r  = tid >> 4;
        int cl = tid & 15;
#pragma unroll
        for (int ti = 0; ti < 5; ++ti)
#pragma unroll
            for (int tj = ti; tj < 5; ++tj) {
                int row = 16 * ti + r, col = 16 * tj + cl;
                atomicAdd(&G[row * NC + col], Gs[row * NC + col]);
            }
    }
}

// Stage 2: target = cooc/(count+eps) + eye ; smooth-L1-ish ; mean -> out[0]
__global__ __launch_bounds__(256) void loss_kernel(const float* __restrict__ pre_adj,
                                                   const float* __restrict__ G,
                                                   float* __restrict__ out) {
    const int tid = threadIdx.x;
    float sum = 0.f;
    for (int u = tid; u < NC * NC; u += 256) {
        int i = u / NC, j = u - i * NC;
        float target;
        if (i == j) {
            target = 1.0f;
        } else {
            // G stored only for tile(i) <= tile(j); G is symmetric
            float num = ((i >> 4) <= (j >> 4)) ? G[i * NC + j] : G[j * NC + i];
            float cnt = G[i * NC + i];            // count[i] = diag (binary labels)
            target = num / (cnt + 1e-7f);
        }
        float r = fabsf(pre_adj[u] - target);
        sum += (r < 1.0f) ? r * r : (r - 0.5f);
    }
    // wave reduce (64 lanes) then cross-wave via LDS
#pragma unroll
    for (int off = 32; off > 0; off >>= 1) sum += __shfl_down(sum, off);
    __shared__ float ws[4];
    if ((tid & 63) == 0) ws[tid >> 6] = sum;
    __syncthreads();
    if (tid == 0) out[0] = (ws[0] + ws[1] + ws[2] + ws[3]) * (1.0f / 6400.0f);
}

extern "C" void kernel_launch(void* const* d_in, const int* in_sizes, int n_in,
                              void* d_out, int out_size, void* d_ws, size_t ws_size,
                              hipStream_t stream) {
    const float* pre_adj = (const float*)d_in[0];   // [80,80]
    const float* label   = (const float*)d_in[1];   // [1048576,80]
    float* out = (float*)d_out;                     // scalar
    float* G   = (float*)d_ws;                      // 80*80 fp32 accumulator

    hipMemsetAsync(G, 0, NC * NC * sizeof(float), stream);
    gram_kernel<<<NBLK, NTHR, 0, stream>>>(label, G);
    loss_kernel<<<1, 256, 0, stream>>>(pre_adj, G, out);
}